// Round 4
// baseline (509.784 us; speedup 1.0000x reference)
//
#include <hip/hip_runtime.h>

#define N_NODES 20000
#define N_EDGES 320000
#define FF 64
#define KK 32

__device__ __forceinline__ float bf2f(unsigned short h) {
    return __uint_as_float(((unsigned)h) << 16);
}
__device__ __forceinline__ unsigned short f2bf(float x) {
    unsigned u = __float_as_uint(x);
    unsigned r = (u + 0x7FFFu + ((u >> 16) & 1u)) >> 16;
    return (unsigned short)r;
}

__global__ __launch_bounds__(256) void hist_k(const int* __restrict__ dst,
                                              int* __restrict__ cnt) {
    int e = blockIdx.x * 256 + threadIdx.x;
    if (e >= N_EDGES) return;
    atomicAdd(&cnt[dst[e]], 1);
}

__global__ __launch_bounds__(1024) void scan_k(const int* __restrict__ cnt,
                                               int* __restrict__ rowptr) {
    __shared__ int part[1024];
    int t = threadIdx.x;
    const int CH = 20;
    int lo = t * CH;
    int hi = lo + CH; if (hi > N_NODES) hi = N_NODES;
    int s = 0;
    for (int i = lo; i < hi && lo < N_NODES; ++i) s += cnt[i];
    if (lo >= N_NODES) s = 0;
    part[t] = s;
    __syncthreads();
    for (int off = 1; off < 1024; off <<= 1) {
        int tmp = (t >= off) ? part[t - off] : 0;
        __syncthreads();
        part[t] += tmp;
        __syncthreads();
    }
    int excl = part[t] - s;
    if (lo < N_NODES) {
        int run = excl;
        for (int i = lo; i < hi; ++i) { rowptr[i] = run; run += cnt[i]; }
    }
    if (t == 1023) rowptr[N_NODES] = part[1023];
}

__global__ __launch_bounds__(256) void scatter_k(const float* __restrict__ coords,
                                                 const int* __restrict__ dst,
                                                 const int* __restrict__ src,
                                                 const int* __restrict__ rowptr,
                                                 int* __restrict__ fill,
                                                 int* __restrict__ esrc,
                                                 float4* __restrict__ egeom) {
    int e = blockIdx.x * 256 + threadIdx.x;
    if (e >= N_EDGES) return;
    int di = dst[e], si = src[e];
    int pos = rowptr[di] + atomicAdd(&fill[di], 1);
    float rx = coords[di*3+0] - coords[si*3+0];
    float ry = coords[di*3+1] - coords[si*3+1];
    float rz = coords[di*3+2] - coords[si*3+2];
    float d = sqrtf(rx*rx + ry*ry + rz*rz + 1e-12f);
    float inv = 1.0f / d;
    esrc[pos] = si;
    egeom[pos] = make_float4(d, rx*inv, ry*inv, rz*inv);
}

// G[e][f] = sum_k rbf(d_e)[k] * Wb[k][f], bf16 out. Tile = 64 edges.
#define GT 64
__global__ __launch_bounds__(256) void gmat_k(const float4* __restrict__ egeom,
                                              const float* __restrict__ Wb,
                                              unsigned short* __restrict__ G) {
    __shared__ float Wl[KK*FF];     // 8 KB
    __shared__ float rbf[GT*KK];    // 8 KB
    __shared__ float dl[GT];
    int t = threadIdx.x;
    for (int i = t; i < KK*FF; i += 256) Wl[i] = Wb[i];
    const float wdt = 2.5f / 31.0f, inv_w = 31.0f / 2.5f;
    int f = t & 63, eb = t >> 6;
    for (int tile = blockIdx.x; tile < N_EDGES/GT; tile += gridDim.x) {
        int e0 = tile * GT;
        __syncthreads();                 // previous iter's readers done (+ Wl on iter 0)
        if (t < GT) dl[t] = egeom[e0 + t].x;
        __syncthreads();
        for (int idx = t; idx < GT*KK; idx += 256) {
            int e = idx >> 5, k = idx & 31;
            float tt = (dl[e] - wdt*(float)k) * inv_w;
            rbf[idx] = __expf(-tt * tt);
        }
        __syncthreads();
        #pragma unroll
        for (int i = 0; i < GT/4; ++i) {
            int e = eb + i*4;
            float acc = 0.f;
            #pragma unroll
            for (int k = 0; k < KK; ++k) acc += rbf[e*KK + k] * Wl[k*64 + f];
            G[(size_t)(e0 + e)*64 + f] = f2bf(acc);
        }
    }
}

// node_in: grid-stride, 8 nodes per block-iteration, weights staged once per block.
__global__ __launch_bounds__(256) void node_in_k(const float* __restrict__ x_dftb,
                                                 const float* __restrict__ W0,
                                                 const float* __restrict__ W1,
                                                 const float* __restrict__ bin,
                                                 float* __restrict__ x,
                                                 ushort4* __restrict__ xb) {
    __shared__ float Wl[2*64*64];   // 32 KB
    __shared__ float xin[8*256];    // 8 KB
    int t = threadIdx.x;
    for (int i = t; i < 8192; i += 256) Wl[i] = (i < 4096) ? W0[i] : W1[i-4096];
    int q = t >> 6, f = t & 63;
    float bb = bin[f];
    for (int base = blockIdx.x*8; base < N_NODES; base += gridDim.x*8) {
        __syncthreads();
        for (int i = t; i < 8*256; i += 256) xin[i] = x_dftb[(size_t)base*256 + i];
        __syncthreads();
        for (int nn = q; nn < 8; nn += 4) {
            const float* xi = xin + nn*256;
            float a0 = bb, a1 = 0.f, a2 = 0.f, a3 = 0.f;
            #pragma unroll
            for (int k = 0; k < 64; ++k) {
                float w0 = Wl[k*64 + f];
                float w1 = Wl[4096 + k*64 + f];
                a0 += xi[k]       * w0;
                a1 += xi[64 + k]  * w1;
                a2 += xi[128 + k] * w1;
                a3 += xi[192 + k] * w1;
            }
            int n = base + nn;
            *(float4*)(x + (size_t)n*256 + f*4) = make_float4(a0, a1, a2, a3);
            if (xb) {
                ushort4 h; h.x = f2bf(a0); h.y = f2bf(a1); h.z = f2bf(a2); h.w = f2bf(a3);
                xb[(size_t)n*64 + f] = h;
            }
        }
    }
}

// MODE 2: precomputed bf16 G + bf16 gathers (no shfl).
// MODE 1: in-kernel shfl G + bf16 gathers.  MODE 0: shfl G + f32 gathers.
template<int MODE>
__global__ __launch_bounds__(256) void msg_k(const int* __restrict__ rowptr,
                                             const int* __restrict__ esrc,
                                             const float4* __restrict__ egeom,
                                             const unsigned short* __restrict__ Gm,
                                             const float* __restrict__ Wb,
                                             const float* __restrict__ bbv,
                                             const float* __restrict__ pw,
                                             const float* __restrict__ xo_f,
                                             const ushort4* __restrict__ xo_b,
                                             float* __restrict__ xn_f,
                                             ushort4* __restrict__ xn_b) {
    int t = threadIdx.x;
    int n = blockIdx.x * 4 + (t >> 6);
    int f = t & 63;

    float wreg[KK];
    if (MODE < 2) {
        #pragma unroll
        for (int k = 0; k < KK; ++k) wreg[k] = Wb[k*64 + f];
    }

    float4 self = *(const float4*)(xo_f + (size_t)n*256 + f*4);
    float acc0 = self.x, acc1 = self.y, acc2 = self.z, acc3 = self.w;

    float b_f = bbv[f];
    float p0 = pw[f], p1 = pw[64+f], p2 = pw[128+f], p3 = pw[192+f], p4 = pw[256+f];
    const float wdt = 2.5f / 31.0f, inv_w = 31.0f / 2.5f;
    float ck = wdt * (float)(f & 31);

    int beg = rowptr[n], end = rowptr[n+1];
    int e = beg;
    for (; e + 4 <= end; e += 4) {
        int si[4];
        float4 gg[4];
        float G[4];
        #pragma unroll
        for (int j = 0; j < 4; ++j) { si[j] = esrc[e+j]; gg[j] = egeom[e+j]; }
        if (MODE == 2) {
            #pragma unroll
            for (int j = 0; j < 4; ++j) G[j] = bf2f(Gm[(size_t)(e+j)*64 + f]);
        }

        float A[4][4];
        if (MODE >= 1) {
            #pragma unroll
            for (int j = 0; j < 4; ++j) {
                ushort4 h = xo_b[(size_t)si[j]*64 + f];
                A[j][0] = bf2f(h.x); A[j][1] = bf2f(h.y);
                A[j][2] = bf2f(h.z); A[j][3] = bf2f(h.w);
            }
        } else {
            #pragma unroll
            for (int j = 0; j < 4; ++j) {
                float4 v = *(const float4*)(xo_f + (size_t)si[j]*256 + f*4);
                A[j][0] = v.x; A[j][1] = v.y; A[j][2] = v.z; A[j][3] = v.w;
            }
        }

        if (MODE < 2) {
            float rb[4];
            #pragma unroll
            for (int j = 0; j < 4; ++j) {
                float tt = (gg[j].x - ck) * inv_w;
                rb[j] = __expf(-tt * tt);
            }
            G[0] = G[1] = G[2] = G[3] = 0.f;
            #pragma unroll
            for (int k = 0; k < KK; ++k) {
                float w = wreg[k];
                #pragma unroll
                for (int j = 0; j < 4; ++j) G[j] += __shfl(rb[j], k, 64) * w;
            }
        }

        #pragma unroll
        for (int j = 0; j < 4; ++j) {
            float g0v = G[j] + b_f;
            float dotav = A[j][1]*gg[j].y + A[j][2]*gg[j].z + A[j][3]*gg[j].w;
            acc0 += p0*A[j][0]*g0v + p1*dotav*G[j];
            float tA = p2*A[j][0]*G[j], tB = p3*g0v, tC = p4*G[j];
            acc1 += tA*gg[j].y + tB*A[j][1] + tC*(A[j][2]*gg[j].w - A[j][3]*gg[j].z);
            acc2 += tA*gg[j].z + tB*A[j][2] + tC*(A[j][3]*gg[j].y - A[j][1]*gg[j].w);
            acc3 += tA*gg[j].w + tB*A[j][3] + tC*(A[j][1]*gg[j].z - A[j][2]*gg[j].y);
        }
    }
    for (; e < end; ++e) {
        int sj = esrc[e];
        float4 g4 = egeom[e];
        float a0, av0, av1, av2;
        if (MODE >= 1) {
            ushort4 h = xo_b[(size_t)sj*64 + f];
            a0 = bf2f(h.x); av0 = bf2f(h.y); av1 = bf2f(h.z); av2 = bf2f(h.w);
        } else {
            float4 v = *(const float4*)(xo_f + (size_t)sj*256 + f*4);
            a0 = v.x; av0 = v.y; av1 = v.z; av2 = v.w;
        }
        float Gs;
        if (MODE == 2) {
            Gs = bf2f(Gm[(size_t)e*64 + f]);
        } else {
            float tt = (g4.x - ck) * inv_w;
            float my_rbf = __expf(-tt * tt);
            Gs = 0.f;
            #pragma unroll
            for (int k = 0; k < KK; ++k) Gs += __shfl(my_rbf, k, 64) * wreg[k];
        }
        float g0v = Gs + b_f;
        float dotav = av0*g4.y + av1*g4.z + av2*g4.w;
        acc0 += p0*a0*g0v + p1*dotav*Gs;
        float tA = p2*a0*Gs, tB = p3*g0v, tC = p4*Gs;
        acc1 += tA*g4.y + tB*av0 + tC*(av1*g4.w - av2*g4.z);
        acc2 += tA*g4.z + tB*av1 + tC*(av2*g4.y - av0*g4.w);
        acc3 += tA*g4.w + tB*av2 + tC*(av0*g4.z - av1*g4.y);
    }

    *(float4*)(xn_f + (size_t)n*256 + f*4) = make_float4(acc0, acc1, acc2, acc3);
    if (MODE >= 1) {
        ushort4 h; h.x = f2bf(acc0); h.y = f2bf(acc1); h.z = f2bf(acc2); h.w = f2bf(acc3);
        xn_b[(size_t)n*64 + f] = h;
    }
}

__global__ __launch_bounds__(256) void node_out_k(const float* __restrict__ x,
                                                  const float* __restrict__ W0,
                                                  const float* __restrict__ W1,
                                                  const float* __restrict__ bout,
                                                  float* __restrict__ out) {
    int n = blockIdx.x * 4 + (threadIdx.x >> 6);
    int f = threadIdx.x & 63;
    float w0 = W0[f], w1 = W1[f];
    float4 v = *(const float4*)(x + (size_t)n*256 + f*4);
    float s0 = v.x * w0, s1 = v.y * w1, s2 = v.z * w1, s3 = v.w * w1;
    #pragma unroll
    for (int off = 32; off >= 1; off >>= 1) {
        s0 += __shfl_down(s0, off, 64);
        s1 += __shfl_down(s1, off, 64);
        s2 += __shfl_down(s2, off, 64);
        s3 += __shfl_down(s3, off, 64);
    }
    if (f == 0) {
        float b = bout[0];
        out[n*4 + 0] = s0 + b;
        out[n*4 + 1] = s1;
        out[n*4 + 2] = s2;
        out[n*4 + 3] = s3;
    }
}

extern "C" void kernel_launch(void* const* d_in, const int* in_sizes, int n_in,
                              void* d_out, int out_size, void* d_ws, size_t ws_size,
                              hipStream_t stream) {
    const float* x_dftb  = (const float*)d_in[0];
    const float* coords  = (const float*)d_in[1];
    const int*   dst     = (const int*)  d_in[2];
    const int*   src     = (const int*)  d_in[3];
    const float* W_in0   = (const float*)d_in[4];
    const float* W_in1   = (const float*)d_in[5];
    const float* b_in    = (const float*)d_in[6];
    const float* W_basis = (const float*)d_in[7];
    const float* b_basis = (const float*)d_in[8];
    const float* path_w  = (const float*)d_in[9];
    const float* W_out0  = (const float*)d_in[10];
    const float* W_out1  = (const float*)d_in[11];
    const float* b_out   = (const float*)d_in[12];
    float* out = (float*)d_out;

    const size_t XF = (size_t)N_NODES * 256 * 4;     // 20.48 MB
    const size_t XB = (size_t)N_NODES * 64 * 8;      // 10.24 MB
    const size_t GB = (size_t)N_EDGES * 64 * 2;      // 40.96 MB
    const size_t EG = (size_t)N_EDGES * 16;
    const size_t ES = (size_t)N_EDGES * 4;
    const size_t SMALL = (size_t)(N_NODES+1)*4 + 12 + (size_t)N_NODES*4*2;
    const size_t need2 = 2*XF + 2*XB + GB + EG + ES + SMALL;
    const size_t need1 = 2*XF + 2*XB + EG + ES + SMALL;
    int mode = (ws_size >= need2) ? 2 : (ws_size >= need1) ? 1 : 0;

    char* p = (char*)d_ws;
    float*   xA = (float*)p;    p += XF;
    float*   xB = (float*)p;    p += XF;
    ushort4* bA = nullptr; ushort4* bB = nullptr;
    unsigned short* Gm = nullptr;
    if (mode >= 1) { bA = (ushort4*)p; p += XB; bB = (ushort4*)p; p += XB; }
    if (mode == 2) { Gm = (unsigned short*)p; p += GB; }
    float4* egeom  = (float4*)p;  p += EG;
    int*    esrc   = (int*)p;     p += ES;
    int*    rowptr = (int*)p;     p += ((size_t)(N_NODES+1)*4 + 12) & ~(size_t)15;
    int*    cnt    = (int*)p;     p += (size_t)N_NODES*4;
    int*    fill   = (int*)p;     p += (size_t)N_NODES*4;

    hipMemsetAsync(cnt,  0, (size_t)N_NODES*4, stream);
    hipMemsetAsync(fill, 0, (size_t)N_NODES*4, stream);

    hist_k   <<<(N_EDGES+255)/256, 256, 0, stream>>>(dst, cnt);
    scan_k   <<<1, 1024, 0, stream>>>(cnt, rowptr);
    scatter_k<<<(N_EDGES+255)/256, 256, 0, stream>>>(coords, dst, src, rowptr, fill,
                                                     esrc, egeom);
    node_in_k<<<625, 256, 0, stream>>>(x_dftb, W_in0, W_in1, b_in, xA, bA);

    float*   xo = xA; float*   xn = xB;
    ushort4* bo = bA; ushort4* bn = bB;
    for (int i = 0; i < 3; ++i) {
        if (mode == 2) {
            gmat_k<<<1024, 256, 0, stream>>>(egeom, W_basis + i*KK*FF, Gm);
            msg_k<2><<<N_NODES/4, 256, 0, stream>>>(rowptr, esrc, egeom, Gm,
                                                    W_basis + i*KK*FF, b_basis + i*FF,
                                                    path_w + i*5*FF, xo, bo, xn, bn);
        } else if (mode == 1) {
            msg_k<1><<<N_NODES/4, 256, 0, stream>>>(rowptr, esrc, egeom, nullptr,
                                                    W_basis + i*KK*FF, b_basis + i*FF,
                                                    path_w + i*5*FF, xo, bo, xn, bn);
        } else {
            msg_k<0><<<N_NODES/4, 256, 0, stream>>>(rowptr, esrc, egeom, nullptr,
                                                    W_basis + i*KK*FF, b_basis + i*FF,
                                                    path_w + i*5*FF, xo, nullptr, xn, nullptr);
        }
        float* tf = xo; xo = xn; xn = tf;
        ushort4* tb = bo; bo = bn; bn = tb;
    }
    node_out_k<<<N_NODES/4, 256, 0, stream>>>(xo, W_out0, W_out1, b_out, out);
}

// Round 5
// 390.502 us; speedup vs baseline: 1.3055x; 1.3055x over previous
//
#include <hip/hip_runtime.h>

#define N_NODES 20000
#define N_EDGES 320000
#define FF 64
#define KK 32

__device__ __forceinline__ float bf2f(unsigned short h) {
    return __uint_as_float(((unsigned)h) << 16);
}
__device__ __forceinline__ unsigned short f2bf(float x) {
    unsigned u = __float_as_uint(x);
    unsigned r = (u + 0x7FFFu + ((u >> 16) & 1u)) >> 16;
    return (unsigned short)r;
}

__global__ __launch_bounds__(256) void hist_k(const int* __restrict__ dst,
                                              int* __restrict__ cnt) {
    int e = blockIdx.x * 256 + threadIdx.x;
    if (e >= N_EDGES) return;
    atomicAdd(&cnt[dst[e]], 1);
}

__global__ __launch_bounds__(1024) void scan_k(const int* __restrict__ cnt,
                                               int* __restrict__ rowptr) {
    __shared__ int part[1024];
    int t = threadIdx.x;
    const int CH = 20;
    int lo = t * CH;
    int hi = lo + CH; if (hi > N_NODES) hi = N_NODES;
    int s = 0;
    for (int i = lo; i < hi && lo < N_NODES; ++i) s += cnt[i];
    if (lo >= N_NODES) s = 0;
    part[t] = s;
    __syncthreads();
    for (int off = 1; off < 1024; off <<= 1) {
        int tmp = (t >= off) ? part[t - off] : 0;
        __syncthreads();
        part[t] += tmp;
        __syncthreads();
    }
    int excl = part[t] - s;
    if (lo < N_NODES) {
        int run = excl;
        for (int i = lo; i < hi; ++i) { rowptr[i] = run; run += cnt[i]; }
    }
    if (t == 1023) rowptr[N_NODES] = part[1023];
}

__global__ __launch_bounds__(256) void scatter_k(const float* __restrict__ coords,
                                                 const int* __restrict__ dst,
                                                 const int* __restrict__ src,
                                                 const int* __restrict__ rowptr,
                                                 int* __restrict__ fill,
                                                 int* __restrict__ esrc,
                                                 float4* __restrict__ egeom) {
    int e = blockIdx.x * 256 + threadIdx.x;
    if (e >= N_EDGES) return;
    int di = dst[e], si = src[e];
    int pos = rowptr[di] + atomicAdd(&fill[di], 1);
    float rx = coords[di*3+0] - coords[si*3+0];
    float ry = coords[di*3+1] - coords[si*3+1];
    float rz = coords[di*3+2] - coords[si*3+2];
    float d = sqrtf(rx*rx + ry*ry + rz*rz + 1e-12f);
    float inv = 1.0f / d;
    esrc[pos] = si;
    egeom[pos] = make_float4(d, rx*inv, ry*inv, rz*inv);
}

// G[r][e][f] = sum_k rbf(d_e)[k] * Wb[r][k][f], bf16 out.
// Windowed RBF: centers spacing == width -> only 9 centers around d matter
// (dropped terms <= exp(-20.25), ~1e-9 relative).
#define GT 64
template<int NR>
__global__ __launch_bounds__(256) void gmat_k(const float4* __restrict__ egeom,
                                              const float* __restrict__ Wb,
                                              unsigned short* __restrict__ G) {
    __shared__ float Wl[NR*KK*FF];
    __shared__ float rw[GT*10];
    __shared__ float dl[GT];
    __shared__ int   k0s[GT];
    int t = threadIdx.x;
    for (int i = t; i < NR*KK*FF; i += 256) Wl[i] = Wb[i];
    const float wdt = 2.5f / 31.0f, inv_w = 31.0f / 2.5f;
    int f = t & 63, eb = t >> 6;
    for (int tile = blockIdx.x; tile < N_EDGES/GT; tile += gridDim.x) {
        int e0 = tile * GT;
        __syncthreads();                  // prev iter readers done (+ Wl iter 0)
        if (t < GT) {
            float d = egeom[e0 + t].x;
            dl[t] = d;
            int k0 = (int)floorf(d * inv_w + 0.5f) - 4;
            if (k0 < 0) k0 = 0;
            if (k0 > KK - 9) k0 = KK - 9;
            k0s[t] = k0;
        }
        __syncthreads();
        for (int idx = t; idx < GT*9; idx += 256) {
            int e = idx / 9, jj = idx - e*9;
            float tt = (dl[e] - wdt * (float)(k0s[e] + jj)) * inv_w;
            rw[e*10 + jj] = __expf(-tt * tt);
        }
        __syncthreads();
        #pragma unroll
        for (int i = 0; i < GT/4; ++i) {
            int e = eb + i*4;
            int k0 = k0s[e];
            const float* wc = Wl + k0*64 + f;
            float a[NR];
            #pragma unroll
            for (int r = 0; r < NR; ++r) a[r] = 0.f;
            #pragma unroll
            for (int jj = 0; jj < 9; ++jj) {
                float rb = rw[e*10 + jj];
                #pragma unroll
                for (int r = 0; r < NR; ++r) a[r] += rb * wc[r*2048 + jj*64];
            }
            #pragma unroll
            for (int r = 0; r < NR; ++r)
                G[(size_t)r*N_EDGES*64 + (size_t)(e0 + e)*64 + f] = f2bf(a[r]);
        }
    }
}

// node_in: W columns in VGPRs (128 regs), x-row broadcast from LDS.
// Block = 4 nodes/iter (wave q -> node base+q), grid-stride.
__global__ __launch_bounds__(256) void node_in_k(const float* __restrict__ x_dftb,
                                                 const float* __restrict__ W0,
                                                 const float* __restrict__ W1,
                                                 const float* __restrict__ bin,
                                                 float* __restrict__ x,
                                                 ushort4* __restrict__ xb) {
    __shared__ float4 xin4[256];    // 4 nodes x 256 floats
    int t = threadIdx.x;
    int q = t >> 6, f = t & 63;
    float w0r[64], w1r[64];
    #pragma unroll
    for (int k = 0; k < 64; ++k) { w0r[k] = W0[k*64 + f]; w1r[k] = W1[k*64 + f]; }
    float bb = bin[f];
    for (int base = blockIdx.x * 4; base < N_NODES; base += gridDim.x * 4) {
        __syncthreads();
        xin4[t] = *(const float4*)(x_dftb + (size_t)base*256 + t*4);
        __syncthreads();
        const float4* xi4 = xin4 + q*64;
        float a0 = bb, a1 = 0.f, a2 = 0.f, a3 = 0.f;
        #pragma unroll
        for (int j = 0; j < 16; ++j) {
            float4 x0 = xi4[j];
            float4 x1 = xi4[16 + j];
            float4 x2 = xi4[32 + j];
            float4 x3 = xi4[48 + j];
            a0 += x0.x*w0r[4*j] + x0.y*w0r[4*j+1] + x0.z*w0r[4*j+2] + x0.w*w0r[4*j+3];
            a1 += x1.x*w1r[4*j] + x1.y*w1r[4*j+1] + x1.z*w1r[4*j+2] + x1.w*w1r[4*j+3];
            a2 += x2.x*w1r[4*j] + x2.y*w1r[4*j+1] + x2.z*w1r[4*j+2] + x2.w*w1r[4*j+3];
            a3 += x3.x*w1r[4*j] + x3.y*w1r[4*j+1] + x3.z*w1r[4*j+2] + x3.w*w1r[4*j+3];
        }
        int n = base + q;
        *(float4*)(x + (size_t)n*256 + f*4) = make_float4(a0, a1, a2, a3);
        if (xb) {
            ushort4 h; h.x = f2bf(a0); h.y = f2bf(a1); h.z = f2bf(a2); h.w = f2bf(a3);
            xb[(size_t)n*64 + f] = h;
        }
    }
}

// One wave per dst node. Coop-load edge ids/geometry (coalesced), broadcast via
// shfl, 8-edge batches: 16 independent gathers in flight per batch.
__global__ __launch_bounds__(256) void msg_fast_k(const int* __restrict__ rowptr,
                                                  const int* __restrict__ esrc,
                                                  const float4* __restrict__ egeom,
                                                  const unsigned short* __restrict__ Gm,
                                                  const float* __restrict__ bbv,
                                                  const float* __restrict__ pw,
                                                  const float* __restrict__ xo_f,
                                                  const ushort4* __restrict__ xo_b,
                                                  float* __restrict__ xn_f,
                                                  ushort4* __restrict__ xn_b) {
    int t = threadIdx.x;
    int n = blockIdx.x * 4 + (t >> 6);
    int f = t & 63;

    float4 self = *(const float4*)(xo_f + (size_t)n*256 + f*4);
    float acc0 = self.x, acc1 = self.y, acc2 = self.z, acc3 = self.w;

    float b_f = bbv[f];
    float p0 = pw[f], p1 = pw[64+f], p2 = pw[128+f], p3 = pw[192+f], p4 = pw[256+f];

    int beg = rowptr[n], end = rowptr[n+1];
    for (int cbase = beg; cbase < end; cbase += 64) {
        int cnt = end - cbase; if (cnt > 64) cnt = 64;
        int ce = cbase + f;
        int sv = 0;
        float gy = 0.f, gz = 0.f, gw = 0.f;
        if (ce < end) {
            sv = esrc[ce];
            float4 g4 = egeom[ce];
            gy = g4.y; gz = g4.z; gw = g4.w;
        }
        for (int j0 = 0; j0 < cnt; j0 += 8) {
            int nb = cnt - j0; if (nb > 8) nb = 8;
            int si[8]; float G[8];
            float A0[8], A1[8], A2[8], A3[8];
            #pragma unroll
            for (int j = 0; j < 8; ++j) si[j] = __shfl(sv, j0 + j, 64);
            #pragma unroll
            for (int j = 0; j < 8; ++j) {
                int ee = cbase + j0 + j;
                int eg = (ee < N_EDGES) ? ee : (N_EDGES - 1);
                G[j] = bf2f(Gm[(size_t)eg*64 + f]);
                ushort4 h = xo_b[(size_t)si[j]*64 + f];
                bool v = (j < nb);
                A0[j] = v ? bf2f(h.x) : 0.f;
                A1[j] = v ? bf2f(h.y) : 0.f;
                A2[j] = v ? bf2f(h.z) : 0.f;
                A3[j] = v ? bf2f(h.w) : 0.f;
            }
            #pragma unroll
            for (int j = 0; j < 8; ++j) {
                float ry = __shfl(gy, j0 + j, 64);
                float rz = __shfl(gz, j0 + j, 64);
                float rw_ = __shfl(gw, j0 + j, 64);
                float g0v = G[j] + b_f;
                float dotav = A1[j]*ry + A2[j]*rz + A3[j]*rw_;
                acc0 += p0*A0[j]*g0v + p1*dotav*G[j];
                float tA = p2*A0[j]*G[j], tB = p3*g0v, tC = p4*G[j];
                acc1 += tA*ry  + tB*A1[j] + tC*(A2[j]*rw_ - A3[j]*rz);
                acc2 += tA*rz  + tB*A2[j] + tC*(A3[j]*ry  - A1[j]*rw_);
                acc3 += tA*rw_ + tB*A3[j] + tC*(A1[j]*rz  - A2[j]*ry);
            }
        }
    }

    *(float4*)(xn_f + (size_t)n*256 + f*4) = make_float4(acc0, acc1, acc2, acc3);
    ushort4 h; h.x = f2bf(acc0); h.y = f2bf(acc1); h.z = f2bf(acc2); h.w = f2bf(acc3);
    xn_b[(size_t)n*64 + f] = h;
}

// Legacy fallback (no Gm buffer): in-kernel shfl-G; f32 or bf16 gathers.
template<int MODE>
__global__ __launch_bounds__(256) void msg_slow_k(const int* __restrict__ rowptr,
                                                  const int* __restrict__ esrc,
                                                  const float4* __restrict__ egeom,
                                                  const float* __restrict__ Wb,
                                                  const float* __restrict__ bbv,
                                                  const float* __restrict__ pw,
                                                  const float* __restrict__ xo_f,
                                                  const ushort4* __restrict__ xo_b,
                                                  float* __restrict__ xn_f,
                                                  ushort4* __restrict__ xn_b) {
    int t = threadIdx.x;
    int n = blockIdx.x * 4 + (t >> 6);
    int f = t & 63;
    float wreg[KK];
    #pragma unroll
    for (int k = 0; k < KK; ++k) wreg[k] = Wb[k*64 + f];
    float4 self = *(const float4*)(xo_f + (size_t)n*256 + f*4);
    float acc0 = self.x, acc1 = self.y, acc2 = self.z, acc3 = self.w;
    float b_f = bbv[f];
    float p0 = pw[f], p1 = pw[64+f], p2 = pw[128+f], p3 = pw[192+f], p4 = pw[256+f];
    const float wdt = 2.5f / 31.0f, inv_w = 31.0f / 2.5f;
    float ck = wdt * (float)(f & 31);
    int beg = rowptr[n], end = rowptr[n+1];
    for (int e = beg; e < end; ++e) {
        int sj = esrc[e];
        float4 g4 = egeom[e];
        float a0, av0, av1, av2;
        if (MODE >= 1) {
            ushort4 h = xo_b[(size_t)sj*64 + f];
            a0 = bf2f(h.x); av0 = bf2f(h.y); av1 = bf2f(h.z); av2 = bf2f(h.w);
        } else {
            float4 v = *(const float4*)(xo_f + (size_t)sj*256 + f*4);
            a0 = v.x; av0 = v.y; av1 = v.z; av2 = v.w;
        }
        float tt = (g4.x - ck) * inv_w;
        float my_rbf = __expf(-tt * tt);
        float Gs = 0.f;
        #pragma unroll
        for (int k = 0; k < KK; ++k) Gs += __shfl(my_rbf, k, 64) * wreg[k];
        float g0v = Gs + b_f;
        float dotav = av0*g4.y + av1*g4.z + av2*g4.w;
        acc0 += p0*a0*g0v + p1*dotav*Gs;
        float tA = p2*a0*Gs, tB = p3*g0v, tC = p4*Gs;
        acc1 += tA*g4.y + tB*av0 + tC*(av1*g4.w - av2*g4.z);
        acc2 += tA*g4.z + tB*av1 + tC*(av2*g4.y - av0*g4.w);
        acc3 += tA*g4.w + tB*av2 + tC*(av0*g4.z - av1*g4.y);
    }
    *(float4*)(xn_f + (size_t)n*256 + f*4) = make_float4(acc0, acc1, acc2, acc3);
    if (MODE >= 1) {
        ushort4 h; h.x = f2bf(acc0); h.y = f2bf(acc1); h.z = f2bf(acc2); h.w = f2bf(acc3);
        xn_b[(size_t)n*64 + f] = h;
    }
}

__global__ __launch_bounds__(256) void node_out_k(const float* __restrict__ x,
                                                  const float* __restrict__ W0,
                                                  const float* __restrict__ W1,
                                                  const float* __restrict__ bout,
                                                  float* __restrict__ out) {
    int n = blockIdx.x * 4 + (threadIdx.x >> 6);
    int f = threadIdx.x & 63;
    float w0 = W0[f], w1 = W1[f];
    float4 v = *(const float4*)(x + (size_t)n*256 + f*4);
    float s0 = v.x * w0, s1 = v.y * w1, s2 = v.z * w1, s3 = v.w * w1;
    #pragma unroll
    for (int off = 32; off >= 1; off >>= 1) {
        s0 += __shfl_down(s0, off, 64);
        s1 += __shfl_down(s1, off, 64);
        s2 += __shfl_down(s2, off, 64);
        s3 += __shfl_down(s3, off, 64);
    }
    if (f == 0) {
        float b = bout[0];
        out[n*4 + 0] = s0 + b;
        out[n*4 + 1] = s1;
        out[n*4 + 2] = s2;
        out[n*4 + 3] = s3;
    }
}

extern "C" void kernel_launch(void* const* d_in, const int* in_sizes, int n_in,
                              void* d_out, int out_size, void* d_ws, size_t ws_size,
                              hipStream_t stream) {
    const float* x_dftb  = (const float*)d_in[0];
    const float* coords  = (const float*)d_in[1];
    const int*   dst     = (const int*)  d_in[2];
    const int*   src     = (const int*)  d_in[3];
    const float* W_in0   = (const float*)d_in[4];
    const float* W_in1   = (const float*)d_in[5];
    const float* b_in    = (const float*)d_in[6];
    const float* W_basis = (const float*)d_in[7];
    const float* b_basis = (const float*)d_in[8];
    const float* path_w  = (const float*)d_in[9];
    const float* W_out0  = (const float*)d_in[10];
    const float* W_out1  = (const float*)d_in[11];
    const float* b_out   = (const float*)d_in[12];
    float* out = (float*)d_out;

    const size_t XF  = (size_t)N_NODES * 256 * 4;   // 20.48 MB
    const size_t XB  = (size_t)N_NODES * 64 * 8;    // 10.24 MB
    const size_t GBp = (size_t)N_EDGES * 64 * 2;    // 40.96 MB per plane
    const size_t EG  = (size_t)N_EDGES * 16;
    const size_t ES  = (size_t)N_EDGES * 4;
    const size_t SMALL = (size_t)(N_NODES+1)*4 + 12 + (size_t)N_NODES*4*2;
    const size_t need3 = 2*XF + 2*XB + 3*GBp + EG + ES + SMALL;
    const size_t need2 = 2*XF + 2*XB + 1*GBp + EG + ES + SMALL;
    const size_t need1 = 2*XF + 2*XB + EG + ES + SMALL;
    int mode = (ws_size >= need3) ? 3 : (ws_size >= need2) ? 2
             : (ws_size >= need1) ? 1 : 0;
    int planes = (mode == 3) ? 3 : (mode == 2) ? 1 : 0;

    char* p = (char*)d_ws;
    float*   xA = (float*)p;    p += XF;
    float*   xB = (float*)p;    p += XF;
    ushort4* bA = nullptr; ushort4* bB = nullptr;
    unsigned short* Gm = nullptr;
    if (mode >= 1) { bA = (ushort4*)p; p += XB; bB = (ushort4*)p; p += XB; }
    if (planes)    { Gm = (unsigned short*)p; p += (size_t)planes * GBp; }
    float4* egeom  = (float4*)p;  p += EG;
    int*    esrc   = (int*)p;     p += ES;
    int*    rowptr = (int*)p;     p += ((size_t)(N_NODES+1)*4 + 12) & ~(size_t)15;
    int*    cnt    = (int*)p;     p += (size_t)N_NODES*4;
    int*    fill   = (int*)p;     p += (size_t)N_NODES*4;

    hipMemsetAsync(cnt,  0, (size_t)N_NODES*4, stream);
    hipMemsetAsync(fill, 0, (size_t)N_NODES*4, stream);

    hist_k   <<<(N_EDGES+255)/256, 256, 0, stream>>>(dst, cnt);
    scan_k   <<<1, 1024, 0, stream>>>(cnt, rowptr);
    scatter_k<<<(N_EDGES+255)/256, 256, 0, stream>>>(coords, dst, src, rowptr, fill,
                                                     esrc, egeom);
    node_in_k<<<1250, 256, 0, stream>>>(x_dftb, W_in0, W_in1, b_in, xA, bA);
    if (mode == 3)
        gmat_k<3><<<2500, 256, 0, stream>>>(egeom, W_basis, Gm);

    float*   xo = xA; float*   xn = xB;
    ushort4* bo = bA; ushort4* bn = bB;
    for (int i = 0; i < 3; ++i) {
        if (mode >= 2) {
            if (mode == 2)
                gmat_k<1><<<2500, 256, 0, stream>>>(egeom, W_basis + i*KK*FF, Gm);
            const unsigned short* Gp = Gm + ((mode == 3) ? (size_t)i*N_EDGES*64 : 0);
            msg_fast_k<<<N_NODES/4, 256, 0, stream>>>(rowptr, esrc, egeom, Gp,
                                                      b_basis + i*FF, path_w + i*5*FF,
                                                      xo, bo, xn, bn);
        } else if (mode == 1) {
            msg_slow_k<1><<<N_NODES/4, 256, 0, stream>>>(rowptr, esrc, egeom,
                                                         W_basis + i*KK*FF, b_basis + i*FF,
                                                         path_w + i*5*FF, xo, bo, xn, bn);
        } else {
            msg_slow_k<0><<<N_NODES/4, 256, 0, stream>>>(rowptr, esrc, egeom,
                                                         W_basis + i*KK*FF, b_basis + i*FF,
                                                         path_w + i*5*FF, xo, nullptr, xn, nullptr);
        }
        float* tf = xo; xo = xn; xn = tf;
        ushort4* tb = bo; bo = bn; bn = tb;
    }
    node_out_k<<<N_NODES/4, 256, 0, stream>>>(xo, W_out0, W_out1, b_out, out);
}